// Round 4
// baseline (2355.396 us; speedup 1.0000x reference)
//
#include <hip/hip_runtime.h>
#include <cstdint>
#include <cstddef>

#define BB  32
#define FF  10
#define NBN 20
#define HH  128
#define GG  5
#define BSTR (FF*NBN*HH)   // 25600
#define FSTR (NBN*HH)      // 2560
#define PADK 132           // [b][k] pad: 132%4==0 keeps float4 alignment, breaks bank stride

struct StageList { int cnt; int cells[20]; };  // packed (r<<16)|(f<<8)|n

__device__ __forceinline__ float sigm(float x) {
  return 1.f / (1.f + __expf(-x));
}
__device__ __forceinline__ float tanh_fast(float x) {
  float e = __expf(-2.f * fabsf(x));
  float t = (1.f - e) / (1.f + e);
  return copysignf(t, x);
}
__device__ __forceinline__ void fma4(float4& a, const float4 w, const float h) {
  a.x = fmaf(w.x, h, a.x); a.y = fmaf(w.y, h, a.y);
  a.z = fmaf(w.z, h, a.z); a.w = fmaf(w.w, h, a.w);
}
__device__ __forceinline__ void add4(float4& a, const float4 b) {
  a.x += b.x; a.y += b.y; a.z += b.z; a.w += b.w;
}

// Boundary vectors (pure functions of inputs).
__global__ void precompute_kernel(
    const float* __restrict__ hid, const float* __restrict__ cell,
    const float* __restrict__ gt,
    float* __restrict__ top_c, float* __restrict__ left_c,
    float* __restrict__ top_h0, float* __restrict__ top_h1,
    float* __restrict__ left_h) {
  int idx = blockIdx.x * 256 + threadIdx.x;
  const int NTOP = BB * NBN * HH;
  const int NLEFT = BB * FF * HH;
  if (idx < NTOP) {
    int h = idx & (HH - 1);
    int n = (idx >> 7) % NBN;
    int b = idx / (HH * NBN);
    const float* hp = hid + (size_t)b * BSTR + n * HH + h;
    const float* cp = cell + (size_t)b * BSTR + n * HH + h;
    float sh = 0.f, sc = 0.f;
#pragma unroll
    for (int f = 0; f < FF; ++f) { sh += hp[f * FSTR]; sc += cp[f * FSTR]; }
    top_c[idx]  = sc * (1.f / FF);
    top_h0[idx] = sh * (1.f / FF);
    top_h1[idx] = (sh + gt[idx]) * (1.f / (FF + 1));
  } else if (idx < NTOP + NLEFT) {
    int j = idx - NTOP;
    int h = j & (HH - 1);
    int f = (j >> 7) % FF;
    int b = j / (HH * FF);
    const float* hp = hid + (size_t)b * BSTR + f * FSTR + h;
    const float* cp = cell + (size_t)b * BSTR + f * FSTR + h;
    float sh = 0.f, sc = 0.f;
#pragma unroll
    for (int n = 0; n < NBN; ++n) { sh += hp[n * HH]; sc += cp[n * HH]; }
    left_c[j] = sc * (1.f / NBN);
    left_h[j] = sh * (1.f / NBN);
  }
}

// Z0 = p.U[0] + bias[0] — dependency-free, 1000 blocks (high occupancy hides latency).
__global__ __launch_bounds__(256)
void z0_kernel(const float* __restrict__ p, const float* __restrict__ U,
               const float* __restrict__ bias, float* __restrict__ Z) {
  __shared__ __align__(16) float xs[HH][36];
  const int cell = blockIdx.x / GG, g = blockIdx.x % GG;
  const int f = cell / NBN, n = cell % NBN;
  const int t = threadIdx.x;
  const int cid = t & 31, bq = t >> 5;
  const int cellofs = f * FSTR + n * HH;

  for (int i = t; i < BB * HH; i += 256) {
    int b = i >> 7, k = i & (HH - 1);
    xs[k][b] = p[(size_t)b * BSTR + cellofs + k];
  }
  __syncthreads();

  const float* wu = U + (size_t)cell * (GG * HH * HH) + (size_t)g * HH * HH + cid * 4;
  float4 bv = *(const float4*)(bias + (size_t)cell * (GG * HH) + g * HH + cid * 4);
  float4 acc[4];
#pragma unroll
  for (int j = 0; j < 4; ++j) acc[j] = bv;

#pragma unroll 4
  for (int k = 0; k < HH; ++k) {
    float4 w = *(const float4*)(wu + (size_t)k * HH);
    float4 x = *(const float4*)&xs[k][bq * 4];
    fma4(acc[0], w, x.x); fma4(acc[1], w, x.y);
    fma4(acc[2], w, x.z); fma4(acc[3], w, x.w);
  }

  float* zp = Z + (size_t)cell * (BB * GG * HH) + (size_t)g * HH + cid * 4;
#pragma unroll
  for (int j = 0; j < 4; ++j)
    *(float4*)(zp + (size_t)(bq * 4 + j) * (GG * HH)) = acc[j];
}

// Dependent GEMV for one stage. grid = cnt*5 blocks, 512 threads (8 waves, 2/SIMD).
// Waves 0-3: k in [0,64); waves 4-7: k in [64,128); LDS reduce at the end.
// Thread tile: 8 cols x 2 batches. r0: Z += ht.Wt + hs.Ws ; r1: Z = x.U + ht.Wt + hs.Ws + b.
__global__ __launch_bounds__(512)
void gemv_stage(const float* __restrict__ U, const float* __restrict__ Wt,
                const float* __restrict__ Ws, const float* __restrict__ bias,
                const float* __restrict__ h0, const float* __restrict__ out_h,
                const float* __restrict__ top_h0, const float* __restrict__ top_h1,
                const float* __restrict__ left_h,
                float* __restrict__ Z, StageList sl) {
  __shared__ __align__(16) float xt[3][BB][PADK];  // [vec][b][k], 50.7 KB

  const int cellIdx = blockIdx.x / GG, g = blockIdx.x % GG;
  const int packed = sl.cells[cellIdx];
  const int r = (packed >> 16) & 0xff;
  const int f = (packed >> 8) & 0xff;
  const int n = packed & 0xff;
  const int t = threadIdx.x;
  const int cid = t & 15;              // 16 col-groups of 8
  const int bsub = (t >> 4) & 3;
  const int wv = t >> 6, wq = wv & 3, kh = wv >> 2;
  const int b0 = wq * 8 + bsub * 2;    // 2 batches: b0, b0+1
  const int col = cid * 8;
  const int cellofs = f * FSTR + n * HH;

  const float* hbase = r ? out_h : h0;
  const float* hp; int hbs;
  if (f > 0) { hp = hbase + cellofs - FSTR; hbs = BSTR; }
  else       { hp = (r ? top_h1 : top_h0) + n * HH; hbs = FSTR; }
  const float* lp; int lbs;
  if (n > 0) { lp = hbase + cellofs - HH; lbs = BSTR; }
  else       { lp = left_h + f * HH; lbs = FF * HH; }

  for (int i = t; i < BB * HH; i += 512) {
    int b = i >> 7, k = i & (HH - 1);
    xt[0][b][k] = hp[(size_t)b * hbs + k];
    xt[1][b][k] = lp[(size_t)b * lbs + k];
    if (r) xt[2][b][k] = h0[(size_t)b * BSTR + cellofs + k];
  }
  __syncthreads();

  const size_t wbase = ((size_t)(r * FF + f) * NBN + n) * ((size_t)GG * HH * HH)
                     + (size_t)g * HH * HH + col + (size_t)(kh * 64) * HH;
  const float* wtp = Wt + wbase;
  const float* wsp = Ws + wbase;
  const float* wup = U + wbase;
  const float* x0 = &xt[0][b0][kh * 64];
  const float* x1 = &xt[0][b0 + 1][kh * 64];
  const float* y0 = &xt[1][b0][kh * 64];
  const float* y1 = &xt[1][b0 + 1][kh * 64];
  const float* v0 = &xt[2][b0][kh * 64];
  const float* v1 = &xt[2][b0 + 1][kh * 64];

  float4 a0A = make_float4(0.f,0.f,0.f,0.f), a0B = a0A, a1A = a0A, a1B = a0A;

  if (r) {
#pragma unroll 2
    for (int kk = 0; kk < 64; kk += 4) {
      float4 hA0 = *(const float4*)(x0 + kk);
      float4 hA1 = *(const float4*)(x1 + kk);
      float4 hB0 = *(const float4*)(y0 + kk);
      float4 hB1 = *(const float4*)(y1 + kk);
      float4 hC0 = *(const float4*)(v0 + kk);
      float4 hC1 = *(const float4*)(v1 + kk);
#define STEP1(j, comp) { \
      float4 wtA = *(const float4*)(wtp + (size_t)(kk + j) * HH); \
      float4 wtB = *(const float4*)(wtp + (size_t)(kk + j) * HH + 4); \
      float4 wsA = *(const float4*)(wsp + (size_t)(kk + j) * HH); \
      float4 wsB = *(const float4*)(wsp + (size_t)(kk + j) * HH + 4); \
      float4 wuA = *(const float4*)(wup + (size_t)(kk + j) * HH); \
      float4 wuB = *(const float4*)(wup + (size_t)(kk + j) * HH + 4); \
      fma4(a0A, wtA, hA0.comp); fma4(a0B, wtB, hA0.comp); \
      fma4(a1A, wtA, hA1.comp); fma4(a1B, wtB, hA1.comp); \
      fma4(a0A, wsA, hB0.comp); fma4(a0B, wsB, hB0.comp); \
      fma4(a1A, wsA, hB1.comp); fma4(a1B, wsB, hB1.comp); \
      fma4(a0A, wuA, hC0.comp); fma4(a0B, wuB, hC0.comp); \
      fma4(a1A, wuA, hC1.comp); fma4(a1B, wuB, hC1.comp); }
      STEP1(0, x) STEP1(1, y) STEP1(2, z) STEP1(3, w)
#undef STEP1
    }
  } else {
#pragma unroll 2
    for (int kk = 0; kk < 64; kk += 4) {
      float4 hA0 = *(const float4*)(x0 + kk);
      float4 hA1 = *(const float4*)(x1 + kk);
      float4 hB0 = *(const float4*)(y0 + kk);
      float4 hB1 = *(const float4*)(y1 + kk);
#define STEP0(j, comp) { \
      float4 wtA = *(const float4*)(wtp + (size_t)(kk + j) * HH); \
      float4 wtB = *(const float4*)(wtp + (size_t)(kk + j) * HH + 4); \
      float4 wsA = *(const float4*)(wsp + (size_t)(kk + j) * HH); \
      float4 wsB = *(const float4*)(wsp + (size_t)(kk + j) * HH + 4); \
      fma4(a0A, wtA, hA0.comp); fma4(a0B, wtB, hA0.comp); \
      fma4(a1A, wtA, hA1.comp); fma4(a1B, wtB, hA1.comp); \
      fma4(a0A, wsA, hB0.comp); fma4(a0B, wsB, hB0.comp); \
      fma4(a1A, wsA, hB1.comp); fma4(a1B, wsB, hB1.comp); }
      STEP0(0, x) STEP0(1, y) STEP0(2, z) STEP0(3, w)
#undef STEP0
    }
  }

  // k-half reduce via LDS (reuse xt space; all compute done => barrier first)
  __syncthreads();
  float* zred = (float*)xt;  // [256][20] padded
  if (t < 256) {
    float* zr = zred + t * 20;
    *(float4*)(zr + 0)  = a0A; *(float4*)(zr + 4)  = a0B;
    *(float4*)(zr + 8)  = a1A; *(float4*)(zr + 12) = a1B;
  }
  __syncthreads();
  if (t >= 256) {
    const float* zr = zred + (size_t)(t - 256) * 20;
    add4(a0A, *(const float4*)(zr + 0));  add4(a0B, *(const float4*)(zr + 4));
    add4(a1A, *(const float4*)(zr + 8));  add4(a1B, *(const float4*)(zr + 12));

    float* zp = Z + (size_t)(f * NBN + n) * (BB * GG * HH) + (size_t)g * HH + col;
    float* zb0 = zp + (size_t)b0 * (GG * HH);
    float* zb1 = zp + (size_t)(b0 + 1) * (GG * HH);
    if (r) {
      const float* bp = bias + (((size_t)(FF + f) * NBN + n) * GG + g) * HH + col;
      float4 bvA = *(const float4*)(bp);
      float4 bvB = *(const float4*)(bp + 4);
      add4(a0A, bvA); add4(a0B, bvB);
      add4(a1A, bvA); add4(a1B, bvB);
      *(float4*)(zb0)     = a0A; *(float4*)(zb0 + 4) = a0B;
      *(float4*)(zb1)     = a1A; *(float4*)(zb1 + 4) = a1B;
    } else {
      float4 o;
      o = *(const float4*)(zb0);     add4(o, a0A); *(float4*)(zb0)     = o;
      o = *(const float4*)(zb0 + 4); add4(o, a0B); *(float4*)(zb0 + 4) = o;
      o = *(const float4*)(zb1);     add4(o, a1A); *(float4*)(zb1)     = o;
      o = *(const float4*)(zb1 + 4); add4(o, a1B); *(float4*)(zb1 + 4) = o;
    }
  }
}

// Gate combine for one stage. grid = cnt blocks, 512 threads.
__global__ __launch_bounds__(512)
void combine_stage(const float* __restrict__ Z,
                   const float* __restrict__ top_c, const float* __restrict__ left_c,
                   float* __restrict__ h0, float* __restrict__ c0,
                   float* __restrict__ out_h, float* __restrict__ out_c,
                   StageList sl) {
  const int packed = sl.cells[blockIdx.x];
  const int r = (packed >> 16) & 0xff;
  const int f = (packed >> 8) & 0xff;
  const int n = packed & 0xff;
  const int t = threadIdx.x;
  const int c = t & (HH - 1), bh = t >> 7;  // 4 groups x 8 batches
  const int cellofs = f * FSTR + n * HH;

  float* hout = r ? out_h : h0;
  float* cout = r ? out_c : c0;
  const float* ctp; int ctbs;
  if (f > 0) { ctp = cout + cellofs - FSTR; ctbs = BSTR; }
  else       { ctp = top_c + n * HH; ctbs = FSTR; }
  const float* clp; int clbs;
  if (n > 0) { clp = cout + cellofs - HH; clbs = BSTR; }
  else       { clp = left_c + f * HH; clbs = FF * HH; }

  const float* zp = Z + (size_t)(f * NBN + n) * (BB * GG * HH) + c;
#pragma unroll
  for (int j = 0; j < 8; ++j) {
    const int b = bh * 8 + j;
    const float* zb = zp + (size_t)b * (GG * HH);
    float zi = zb[0], zfs = zb[HH], zft = zb[2 * HH], zo = zb[3 * HH], zc = zb[4 * HH];
    float clv = clp[(size_t)b * clbs + c];
    float ctv = ctp[(size_t)b * ctbs + c];
    float iv = sigm(zi), fsv = sigm(zfs), ftv = sigm(zft), ov = sigm(zo);
    float cn = tanh_fast(zc);
    float cnew = fmaf(iv, cn, fmaf(fsv, clv, ftv * ctv));
    float hnew = ov * tanh_fast(cnew);
    hout[(size_t)b * BSTR + cellofs + c] = hnew;
    cout[(size_t)b * BSTR + cellofs + c] = cnew;
  }
}

extern "C" void kernel_launch(void* const* d_in, const int* in_sizes, int n_in,
                              void* d_out, int out_size, void* d_ws, size_t ws_size,
                              hipStream_t stream) {
  const float* hid  = (const float*)d_in[0];
  const float* cell = (const float*)d_in[1];
  const float* gt   = (const float*)d_in[2];
  // d_in[3] = global_s_state — dead for R=2
  const float* p    = (const float*)d_in[4];
  const float* U    = (const float*)d_in[5];
  const float* Wt   = (const float*)d_in[6];
  const float* Ws   = (const float*)d_in[7];
  const float* bias = (const float*)d_in[8];

  float* out_h = (float*)d_out;
  float* out_c = out_h + (size_t)BB * BSTR;

  float* w = (float*)d_ws;
  float* h0     = w; w += (size_t)BB * BSTR;
  float* c0     = w; w += (size_t)BB * BSTR;
  float* top_c  = w; w += (size_t)BB * NBN * HH;
  float* left_c = w; w += (size_t)BB * FF * HH;
  float* top_h0 = w; w += (size_t)BB * NBN * HH;
  float* top_h1 = w; w += (size_t)BB * NBN * HH;
  float* left_h = w; w += (size_t)BB * FF * HH;
  float* Z      = w; w += (size_t)FF * NBN * BB * GG * HH;  // 16.4 MB

  const int pre_threads = BB * NBN * HH + BB * FF * HH;
  hipLaunchKernelGGL(precompute_kernel, dim3((pre_threads + 255) / 256), dim3(256),
                     0, stream, hid, cell, gt, top_c, left_c, top_h0, top_h1, left_h);

  hipLaunchKernelGGL(z0_kernel, dim3(FF * NBN * GG), dim3(256), 0, stream,
                     p, U, bias, Z);

  for (int d = 0; d < FF + NBN; ++d) {
    StageList sl; sl.cnt = 0;
    for (int r = 0; r < 2; ++r) {
      int dd = d - r;
      for (int f = 0; f < FF; ++f) {
        int n = dd - f;
        if (n >= 0 && n < NBN) sl.cells[sl.cnt++] = (r << 16) | (f << 8) | n;
      }
    }
    if (sl.cnt == 0) continue;
    hipLaunchKernelGGL(gemv_stage, dim3(sl.cnt * GG), dim3(512), 0, stream,
                       U, Wt, Ws, bias, h0, out_h, top_h0, top_h1, left_h, Z, sl);
    hipLaunchKernelGGL(combine_stage, dim3(sl.cnt), dim3(512), 0, stream,
                       Z, top_c, left_c, h0, c0, out_h, out_c, sl);
  }
}

// Round 5
// 819.578 us; speedup vs baseline: 2.8739x; 2.8739x over previous
//
#include <hip/hip_runtime.h>
#include <cstdint>
#include <cstddef>

#define BB  32
#define FF  10
#define NBN 20
#define HH  128
#define GG  5
#define BSTR (FF*NBN*HH)   // 25600
#define FSTR (NBN*HH)      // 2560
#define XPAD 132           // [b][k] row stride (floats): 16B-aligned, banks shift 4/row

struct StageList { int cnt; int cells[20]; };  // packed (r<<16)|(f<<8)|n

__device__ __forceinline__ float sigm(float x) {
  return 1.f / (1.f + __expf(-x));
}
__device__ __forceinline__ float tanh_fast(float x) {
  float e = __expf(-2.f * fabsf(x));
  float t = (1.f - e) / (1.f + e);
  return copysignf(t, x);
}
__device__ __forceinline__ void fma4(float4& a, const float4 w, const float h) {
  a.x = fmaf(w.x, h, a.x); a.y = fmaf(w.y, h, a.y);
  a.z = fmaf(w.z, h, a.z); a.w = fmaf(w.w, h, a.w);
}
__device__ __forceinline__ void add4(float4& a, const float4 b) {
  a.x += b.x; a.y += b.y; a.z += b.z; a.w += b.w;
}

// Boundary vectors (pure functions of inputs).
__global__ void precompute_kernel(
    const float* __restrict__ hid, const float* __restrict__ cell,
    const float* __restrict__ gt,
    float* __restrict__ top_c, float* __restrict__ left_c,
    float* __restrict__ top_h0, float* __restrict__ top_h1,
    float* __restrict__ left_h) {
  int idx = blockIdx.x * 256 + threadIdx.x;
  const int NTOP = BB * NBN * HH;
  const int NLEFT = BB * FF * HH;
  if (idx < NTOP) {
    int h = idx & (HH - 1);
    int n = (idx >> 7) % NBN;
    int b = idx / (HH * NBN);
    const float* hp = hid + (size_t)b * BSTR + n * HH + h;
    const float* cp = cell + (size_t)b * BSTR + n * HH + h;
    float sh = 0.f, sc = 0.f;
#pragma unroll
    for (int f = 0; f < FF; ++f) { sh += hp[f * FSTR]; sc += cp[f * FSTR]; }
    top_c[idx]  = sc * (1.f / FF);
    top_h0[idx] = sh * (1.f / FF);
    top_h1[idx] = (sh + gt[idx]) * (1.f / (FF + 1));
  } else if (idx < NTOP + NLEFT) {
    int j = idx - NTOP;
    int h = j & (HH - 1);
    int f = (j >> 7) % FF;
    int b = j / (HH * FF);
    const float* hp = hid + (size_t)b * BSTR + f * FSTR + h;
    const float* cp = cell + (size_t)b * BSTR + f * FSTR + h;
    float sh = 0.f, sc = 0.f;
#pragma unroll
    for (int n = 0; n < NBN; ++n) { sh += hp[n * HH]; sc += cp[n * HH]; }
    left_c[j] = sc * (1.f / NBN);
    left_h[j] = sh * (1.f / NBN);
  }
}

// Z0 = p.U[0] + bias[0] — dependency-free. grid = 1000 blocks, 256 threads.
__global__ __launch_bounds__(256, 4)
void z0_kernel(const float* __restrict__ p, const float* __restrict__ U,
               const float* __restrict__ bias, float* __restrict__ Z) {
  __shared__ __align__(16) float xs[HH][36];
  const int cell = blockIdx.x / GG, g = blockIdx.x % GG;
  const int f = cell / NBN, n = cell % NBN;
  const int t = threadIdx.x;
  const int cid = t & 31, bq = t >> 5;
  const int cellofs = f * FSTR + n * HH;

  for (int i = t; i < BB * HH; i += 256) {
    int b = i >> 7, k = i & (HH - 1);
    xs[k][b] = p[(size_t)b * BSTR + cellofs + k];
  }
  __syncthreads();

  const float* wu = U + (size_t)cell * (GG * HH * HH) + (size_t)g * HH * HH + cid * 4;
  float4 bv = *(const float4*)(bias + (size_t)cell * (GG * HH) + g * HH + cid * 4);
  float4 acc[4];
#pragma unroll
  for (int j = 0; j < 4; ++j) acc[j] = bv;

#pragma unroll 4
  for (int k = 0; k < HH; ++k) {
    float4 w = *(const float4*)(wu + (size_t)k * HH);
    float4 x = *(const float4*)&xs[k][bq * 4];
    fma4(acc[0], w, x.x); fma4(acc[1], w, x.y);
    fma4(acc[2], w, x.z); fma4(acc[3], w, x.w);
  }

  float* zp = Z + (size_t)cell * (BB * GG * HH) + (size_t)g * HH + cid * 4;
#pragma unroll
  for (int j = 0; j < 4; ++j)
    *(float4*)(zp + (size_t)(bq * 4 + j) * (GG * HH)) = acc[j];
}

// Dependent GEMV for one stage. grid = cnt*10 (cell, gate, col-half), 256 threads.
// Thread: cg = t&15 (4 cols), bq = (t>>4)&3 (8 batches b=bq+4j), kh = t>>6 (wave = k-quarter).
// r0: Z += ht.Wt + hs.Ws ; r1: Z = x.U + ht.Wt + hs.Ws + bias
__global__ __launch_bounds__(256, 2)
void gemv_stage(const float* __restrict__ U, const float* __restrict__ Wt,
                const float* __restrict__ Ws, const float* __restrict__ bias,
                const float* __restrict__ h0, const float* __restrict__ out_h,
                const float* __restrict__ top_h0, const float* __restrict__ top_h1,
                const float* __restrict__ left_h,
                float* __restrict__ Z, StageList sl) {
  __shared__ __align__(16) float xt[3 * BB * XPAD];  // 50688 B; reused as reduce buf

  const int cellIdx = blockIdx.x / (GG * 2);
  const int sub = blockIdx.x % (GG * 2);
  const int g = sub >> 1, ch = sub & 1;
  const int packed = sl.cells[cellIdx];
  const int r = (packed >> 16) & 0xff;
  const int f = (packed >> 8) & 0xff;
  const int n = packed & 0xff;
  const int t = threadIdx.x;
  const int cg = t & 15, bq = (t >> 4) & 3, kh = t >> 6;
  const int col = ch * 64 + cg * 4;
  const int cellofs = f * FSTR + n * HH;

  const float* hbase = r ? out_h : h0;
  const float* hp; int hbs;
  if (f > 0) { hp = hbase + cellofs - FSTR; hbs = BSTR; }
  else       { hp = (r ? top_h1 : top_h0) + n * HH; hbs = FSTR; }
  const float* lp; int lbs;
  if (n > 0) { lp = hbase + cellofs - HH; lbs = BSTR; }
  else       { lp = left_h + f * HH; lbs = FF * HH; }

  for (int i = t; i < BB * HH; i += 256) {
    int b = i >> 7, k = i & (HH - 1);
    xt[(0 * BB + b) * XPAD + k] = hp[(size_t)b * hbs + k];
    xt[(1 * BB + b) * XPAD + k] = lp[(size_t)b * lbs + k];
    if (r) xt[(2 * BB + b) * XPAD + k] = h0[(size_t)b * BSTR + cellofs + k];
  }
  __syncthreads();

  const size_t wofs = ((size_t)(r * FF + f) * NBN + n) * ((size_t)GG * HH * HH)
                    + (size_t)g * HH * HH + (size_t)(kh * 32) * HH + col;
  const float* wtp = Wt + wofs;
  const float* wsp = Ws + wofs;
  const float* wup = U + wofs;
  const int ka0 = kh * 32;

  float4 acc[8];
#pragma unroll
  for (int i = 0; i < 8; ++i) acc[i] = make_float4(0.f, 0.f, 0.f, 0.f);

  if (r) {
    for (int kk = 0; kk < 32; kk += 4) {
      float4 wT[4], wS[4], wU[4];
#pragma unroll
      for (int j = 0; j < 4; ++j) {
        wT[j] = *(const float4*)(wtp + (size_t)(kk + j) * HH);
        wS[j] = *(const float4*)(wsp + (size_t)(kk + j) * HH);
        wU[j] = *(const float4*)(wup + (size_t)(kk + j) * HH);
      }
      const int ka = ka0 + kk;
#pragma unroll
      for (int i = 0; i < 8; ++i) {
        const int b = bq + 4 * i;
        float4 xT = *(const float4*)&xt[(0 * BB + b) * XPAD + ka];
        float4 xS = *(const float4*)&xt[(1 * BB + b) * XPAD + ka];
        float4 xU = *(const float4*)&xt[(2 * BB + b) * XPAD + ka];
        float4 a = acc[i];
        fma4(a, wT[0], xT.x); fma4(a, wT[1], xT.y); fma4(a, wT[2], xT.z); fma4(a, wT[3], xT.w);
        fma4(a, wS[0], xS.x); fma4(a, wS[1], xS.y); fma4(a, wS[2], xS.z); fma4(a, wS[3], xS.w);
        fma4(a, wU[0], xU.x); fma4(a, wU[1], xU.y); fma4(a, wU[2], xU.z); fma4(a, wU[3], xU.w);
        acc[i] = a;
      }
    }
  } else {
    for (int kk = 0; kk < 32; kk += 4) {
      float4 wT[4], wS[4];
#pragma unroll
      for (int j = 0; j < 4; ++j) {
        wT[j] = *(const float4*)(wtp + (size_t)(kk + j) * HH);
        wS[j] = *(const float4*)(wsp + (size_t)(kk + j) * HH);
      }
      const int ka = ka0 + kk;
#pragma unroll
      for (int i = 0; i < 8; ++i) {
        const int b = bq + 4 * i;
        float4 xT = *(const float4*)&xt[(0 * BB + b) * XPAD + ka];
        float4 xS = *(const float4*)&xt[(1 * BB + b) * XPAD + ka];
        float4 a = acc[i];
        fma4(a, wT[0], xT.x); fma4(a, wT[1], xT.y); fma4(a, wT[2], xT.z); fma4(a, wT[3], xT.w);
        fma4(a, wS[0], xS.x); fma4(a, wS[1], xS.y); fma4(a, wS[2], xS.z); fma4(a, wS[3], xS.w);
        acc[i] = a;
      }
    }
  }

  // k-quarter reduce via LDS (xt reused; all xt reads are done)
  __syncthreads();
  const int lane = t & 63;
  if (kh > 0) {
    float* rp = xt + (size_t)((kh - 1) * 64 + lane) * 36;
#pragma unroll
    for (int i = 0; i < 8; ++i) *(float4*)(rp + 4 * i) = acc[i];
  }
  __syncthreads();
  if (kh == 0) {
#pragma unroll
    for (int q = 0; q < 3; ++q) {
      const float* rp = xt + (size_t)(q * 64 + lane) * 36;
#pragma unroll
      for (int i = 0; i < 8; ++i) add4(acc[i], *(const float4*)(rp + 4 * i));
    }

    float* zbase = Z + (size_t)(f * NBN + n) * (BB * GG * HH) + (size_t)g * HH + col;
    if (r) {
      float4 bv = *(const float4*)(bias + (((size_t)(FF + f) * NBN + n) * GG + g) * HH + col);
#pragma unroll
      for (int i = 0; i < 8; ++i) {
        add4(acc[i], bv);
        *(float4*)(zbase + (size_t)(bq + 4 * i) * (GG * HH)) = acc[i];
      }
    } else {
#pragma unroll
      for (int i = 0; i < 8; ++i) {
        float4* dst = (float4*)(zbase + (size_t)(bq + 4 * i) * (GG * HH));
        float4 o = *dst; add4(o, acc[i]); *dst = o;
      }
    }
  }
}

// Gate combine for one stage. grid = cnt blocks, 512 threads.
__global__ __launch_bounds__(512)
void combine_stage(const float* __restrict__ Z,
                   const float* __restrict__ top_c, const float* __restrict__ left_c,
                   float* __restrict__ h0, float* __restrict__ c0,
                   float* __restrict__ out_h, float* __restrict__ out_c,
                   StageList sl) {
  const int packed = sl.cells[blockIdx.x];
  const int r = (packed >> 16) & 0xff;
  const int f = (packed >> 8) & 0xff;
  const int n = packed & 0xff;
  const int t = threadIdx.x;
  const int c = t & (HH - 1), bh = t >> 7;  // 4 groups x 8 batches
  const int cellofs = f * FSTR + n * HH;

  float* hout = r ? out_h : h0;
  float* cout = r ? out_c : c0;
  const float* ctp; int ctbs;
  if (f > 0) { ctp = cout + cellofs - FSTR; ctbs = BSTR; }
  else       { ctp = top_c + n * HH; ctbs = FSTR; }
  const float* clp; int clbs;
  if (n > 0) { clp = cout + cellofs - HH; clbs = BSTR; }
  else       { clp = left_c + f * HH; clbs = FF * HH; }

  const float* zp = Z + (size_t)(f * NBN + n) * (BB * GG * HH) + c;
#pragma unroll
  for (int j = 0; j < 8; ++j) {
    const int b = bh * 8 + j;
    const float* zb = zp + (size_t)b * (GG * HH);
    float zi = zb[0], zfs = zb[HH], zft = zb[2 * HH], zo = zb[3 * HH], zc = zb[4 * HH];
    float clv = clp[(size_t)b * clbs + c];
    float ctv = ctp[(size_t)b * ctbs + c];
    float iv = sigm(zi), fsv = sigm(zfs), ftv = sigm(zft), ov = sigm(zo);
    float cn = tanh_fast(zc);
    float cnew = fmaf(iv, cn, fmaf(fsv, clv, ftv * ctv));
    float hnew = ov * tanh_fast(cnew);
    hout[(size_t)b * BSTR + cellofs + c] = hnew;
    cout[(size_t)b * BSTR + cellofs + c] = cnew;
  }
}

extern "C" void kernel_launch(void* const* d_in, const int* in_sizes, int n_in,
                              void* d_out, int out_size, void* d_ws, size_t ws_size,
                              hipStream_t stream) {
  const float* hid  = (const float*)d_in[0];
  const float* cell = (const float*)d_in[1];
  const float* gt   = (const float*)d_in[2];
  // d_in[3] = global_s_state — dead for R=2
  const float* p    = (const float*)d_in[4];
  const float* U    = (const float*)d_in[5];
  const float* Wt   = (const float*)d_in[6];
  const float* Ws   = (const float*)d_in[7];
  const float* bias = (const float*)d_in[8];

  float* out_h = (float*)d_out;
  float* out_c = out_h + (size_t)BB * BSTR;

  float* w = (float*)d_ws;
  float* h0     = w; w += (size_t)BB * BSTR;
  float* c0     = w; w += (size_t)BB * BSTR;
  float* top_c  = w; w += (size_t)BB * NBN * HH;
  float* left_c = w; w += (size_t)BB * FF * HH;
  float* top_h0 = w; w += (size_t)BB * NBN * HH;
  float* top_h1 = w; w += (size_t)BB * NBN * HH;
  float* left_h = w; w += (size_t)BB * FF * HH;
  float* Z      = w; w += (size_t)FF * NBN * BB * GG * HH;  // 16.4 MB

  const int pre_threads = BB * NBN * HH + BB * FF * HH;
  hipLaunchKernelGGL(precompute_kernel, dim3((pre_threads + 255) / 256), dim3(256),
                     0, stream, hid, cell, gt, top_c, left_c, top_h0, top_h1, left_h);

  hipLaunchKernelGGL(z0_kernel, dim3(FF * NBN * GG), dim3(256), 0, stream,
                     p, U, bias, Z);

  for (int d = 0; d < FF + NBN; ++d) {
    StageList sl; sl.cnt = 0;
    for (int r = 0; r < 2; ++r) {
      int dd = d - r;
      for (int f = 0; f < FF; ++f) {
        int n = dd - f;
        if (n >= 0 && n < NBN) sl.cells[sl.cnt++] = (r << 16) | (f << 8) | n;
      }
    }
    if (sl.cnt == 0) continue;
    hipLaunchKernelGGL(gemv_stage, dim3(sl.cnt * GG * 2), dim3(256), 0, stream,
                       U, Wt, Ws, bias, h0, out_h, top_h0, top_h1, left_h, Z, sl);
    hipLaunchKernelGGL(combine_stage, dim3(sl.cnt), dim3(512), 0, stream,
                       Z, top_c, left_c, h0, c0, out_h, out_c, sl);
  }
}